// Round 13
// baseline (350.194 us; speedup 1.0000x reference)
//
#include <hip/hip_runtime.h>
#include <hip/hip_bf16.h>
#include <hip/hip_cooperative_groups.h>
#include <math.h>

namespace cg = cooperative_groups;

#define N_NODES 10000
#define MPAD    10112      // 79 * 128
#define N_EDGES 320000
#define NFEAT   512
#define NHID    256
#define NCLASS  40
#define SLOT    96         // max deg bound: Binom(320K,1e-4) max ~55; P(>96) ~ 0
#define CSTRIDE 16         // one counter per 64B line
#define NBM1    158        // gemm1 m-tiles (64 rows)
#define NG1     (NBM1 * 2) // 316 gemm1 blocks (158 m x 2 n)
#define GRID    512
#define GSZ     (GRID * 256)

typedef short  short8  __attribute__((ext_vector_type(8)));
typedef float  floatx4 __attribute__((ext_vector_type(4)));

__device__ __forceinline__ unsigned short f2b(float f) {
  __hip_bfloat16 h = __float2bfloat16(f);
  unsigned short u; __builtin_memcpy(&u, &h, 2); return u;
}
__device__ __forceinline__ float b2f(unsigned short u) {
  return __uint_as_float(((unsigned)u) << 16);
}
__device__ __forceinline__ short8 pack8(float4 a, float4 b) {
  short8 r;
  r[0] = (short)f2b(a.x); r[1] = (short)f2b(a.y); r[2] = (short)f2b(a.z); r[3] = (short)f2b(a.w);
  r[4] = (short)f2b(b.x); r[5] = (short)f2b(b.y); r[6] = (short)f2b(b.z); r[7] = (short)f2b(b.w);
  return r;
}

struct Args {
  const float* x;
  const int*   esrc;
  const int*   edst;
  const float* ew;
  const float* W1;
  const float* b1;
  const float* W2;
  const float* b2;
  float*       out;
  unsigned short* w1t;
  unsigned short* w2t;
  unsigned short* xw1b;
  unsigned short* h;
  float*       hw2;
  int*         cnt;
  int2*        epk;
};

__global__ __launch_bounds__(256) void mega_k(Args a) {
  cg::grid_group grid = cg::this_grid();
  const int bid = blockIdx.x;
  const int t   = threadIdx.x;
  const int gtid = bid * 256 + t;

  __shared__ __align__(16) char smem_raw[24576];   // phase-unioned LDS

  // ---------------- P0: prep — zero cnt, W1->bf16^T, W2->bf16^T padded ----------------
  for (int i = gtid; i < N_NODES * CSTRIDE; i += GSZ) a.cnt[i] = 0;
  for (int i = gtid; i < NFEAT * NHID; i += GSZ) {
    int k = i / NHID, n = i % NHID;
    a.w1t[n * NFEAT + k] = f2b(a.W1[i]);
  }
  for (int i = gtid; i < 64 * NHID; i += GSZ) {
    int n = i >> 8, k = i & 255;
    a.w2t[i] = (n < NCLASS) ? f2b(a.W2[k * NCLASS + n]) : (unsigned short)0;
  }

  grid.sync();

  // ---------------- P1: gemm1 (blocks 0..NG1-1)  ||  scatter (blocks NG1..511) ----------------
  if (bid < NG1) {
    short8* As = (short8*)smem_raw;            // 2 x 64 x 4  = 512 short8 (8 KB)
    short8* Bs = (short8*)(smem_raw + 8192);   // 2 x 128 x 4 = 1024 short8 (16 KB)

    const int l  = t & 63;
    const int wc = t >> 6;
    const int bm = (bid % NBM1) * 64;
    const int bn = (bid / NBM1) * 128;

    const int rowA = t >> 2, sA = t & 3;
    const int rowB = t >> 1, sB = (t & 1) * 2;

    const float4 z4 = make_float4(0.f, 0.f, 0.f, 0.f);
    const floatx4 zero = {0.f, 0.f, 0.f, 0.f};
    floatx4 acc[4][2];
#pragma unroll
    for (int mi = 0; mi < 4; mi++) { acc[mi][0] = zero; acc[mi][1] = zero; }

    const int q = l >> 4;
    const bool arok = (bm + rowA) < N_NODES;
    const float* xrow = &a.x[(size_t)(bm + rowA) * NFEAT + sA * 8];
    const unsigned short* brow = &a.w1t[(size_t)(bn + rowB) * NFEAT + sB * 8];

    {
      float4 a0 = z4, a1 = z4;
      if (arok) { a0 = *(const float4*)(xrow); a1 = *(const float4*)(xrow + 4); }
      short8 b0 = *(const short8*)(brow);
      short8 b1 = *(const short8*)(brow + 8);
      As[rowA * 4 + (sA ^ (rowA & 3))] = pack8(a0, a1);
      Bs[rowB * 4 + ((sB    ) ^ (rowB & 3))] = b0;
      Bs[rowB * 4 + ((sB + 1) ^ (rowB & 3))] = b1;
    }

    for (int s = 0; s < 16; s++) {
      __syncthreads();
      const int cur = s & 1;
      float4 na0 = z4, na1 = z4;
      short8 nb0, nb1;
      const bool more = (s < 15);
      if (more) {
        const int k1 = (s + 1) * 32;
        if (arok) { na0 = *(const float4*)(xrow + k1); na1 = *(const float4*)(xrow + k1 + 4); }
        nb0 = *(const short8*)(brow + k1);
        nb1 = *(const short8*)(brow + k1 + 8);
      }

      short8 af[4], bf[2];
#pragma unroll
      for (int mi = 0; mi < 4; mi++) {
        int ar = mi * 16 + (l & 15);
        af[mi] = As[cur * 256 + ar * 4 + (q ^ (ar & 3))];
      }
#pragma unroll
      for (int ni = 0; ni < 2; ni++) {
        int bc = wc * 32 + ni * 16 + (l & 15);
        bf[ni] = Bs[cur * 512 + bc * 4 + (q ^ (bc & 3))];
      }
#pragma unroll
      for (int mi = 0; mi < 4; mi++)
#pragma unroll
        for (int ni = 0; ni < 2; ni++)
          acc[mi][ni] = __builtin_amdgcn_mfma_f32_16x16x32_bf16(af[mi], bf[ni], acc[mi][ni], 0, 0, 0);

      if (more) {
        const int nxt = cur ^ 1;
        As[nxt * 256 + rowA * 4 + (sA ^ (rowA & 3))] = pack8(na0, na1);
        Bs[nxt * 512 + rowB * 4 + ((sB    ) ^ (rowB & 3))] = nb0;
        Bs[nxt * 512 + rowB * 4 + ((sB + 1) ^ (rowB & 3))] = nb1;
      }
    }

#pragma unroll
    for (int mi = 0; mi < 4; mi++)
#pragma unroll
      for (int ni = 0; ni < 2; ni++) {
        int row = bm + mi * 16 + (l >> 4) * 4;
        int col = bn + wc * 32 + ni * 16 + (l & 15);
#pragma unroll
        for (int r = 0; r < 4; r++)
          a.xw1b[(size_t)(row + r) * NHID + col] = f2b(acc[mi][ni][r]);
      }
  } else {
    // scatter role: 196 blocks, stride loop over edges
    const int SSTRIDE = (GRID - NG1) * 256;    // 50176
    for (int e = (bid - NG1) * 256 + t; e < N_EDGES; e += SSTRIDE) {
      int d = a.edst[e];
      int p = atomicAdd(&a.cnt[d << 4], 1);
      int2 pk; pk.x = a.esrc[e]; pk.y = __float_as_int(a.ew[e]);
      a.epk[d * SLOT + p] = pk;
    }
  }

  grid.sync();

  // ---------------- P2: spmm1 — h = bf16(relu(A * xw1 + b1)) ----------------
  // vb & 7 == bid & 7 (stride 512 multiple of 8) -> XCD slice mapping preserved.
  for (int vb = bid; vb < 5000; vb += GRID) {
    int xcd     = vb & 7;
    int slice   = xcd >> 2;
    int quarter = xcd & 3;
    int wave    = t >> 6;
    int lane    = t & 63;
    int node    = (vb >> 3) * 4 + wave + quarter * 2500;
    int hh      = lane >> 5;
    int f       = lane & 31;
    int fbase   = slice * 128 + f * 4;

    int e0 = node * SLOT;
    int n  = a.cnt[node << 4];
    float a0 = 0.f, a1 = 0.f, a2 = 0.f, a3 = 0.f;
    for (int base = 0; base < n; base += 64) {
      int c2 = n - base; if (c2 > 64) c2 = 64;
      int2 my = make_int2(0, 0);
      if (lane < c2) my = a.epk[e0 + base + lane];
      int j = 0;
      for (; j + 8 <= c2; j += 8) {
#pragma unroll
        for (int p = 0; p < 4; p++) {
          int   idx = j + 2 * p + hh;
          int   s   = __shfl(my.x, idx);
          float wj  = __int_as_float(__shfl(my.y, idx));
          uint2 v = *(const uint2*)&a.xw1b[(size_t)s * NHID + fbase];
          a0 = fmaf(wj, b2f((unsigned short)(v.x & 0xffff)), a0);
          a1 = fmaf(wj, b2f((unsigned short)(v.x >> 16)),    a1);
          a2 = fmaf(wj, b2f((unsigned short)(v.y & 0xffff)), a2);
          a3 = fmaf(wj, b2f((unsigned short)(v.y >> 16)),    a3);
        }
      }
      for (; j < c2; j++) {
        int   s  = __shfl(my.x, j);
        float wj = __int_as_float(__shfl(my.y, j));
        if (hh == 0) {
          uint2 v = *(const uint2*)&a.xw1b[(size_t)s * NHID + fbase];
          a0 = fmaf(wj, b2f((unsigned short)(v.x & 0xffff)), a0);
          a1 = fmaf(wj, b2f((unsigned short)(v.x >> 16)),    a1);
          a2 = fmaf(wj, b2f((unsigned short)(v.y & 0xffff)), a2);
          a3 = fmaf(wj, b2f((unsigned short)(v.y >> 16)),    a3);
        }
      }
    }
    a0 += __shfl_xor(a0, 32);
    a1 += __shfl_xor(a1, 32);
    a2 += __shfl_xor(a2, 32);
    a3 += __shfl_xor(a3, 32);
    if (hh == 0) {
      a0 = fmaxf(a0 + a.b1[fbase + 0], 0.f);
      a1 = fmaxf(a1 + a.b1[fbase + 1], 0.f);
      a2 = fmaxf(a2 + a.b1[fbase + 2], 0.f);
      a3 = fmaxf(a3 + a.b1[fbase + 3], 0.f);
      uint2 po;
      po.x = ((unsigned)f2b(a1) << 16) | f2b(a0);
      po.y = ((unsigned)f2b(a3) << 16) | f2b(a2);
      *(uint2*)&a.h[(size_t)node * NHID + fbase] = po;
    }
  }

  grid.sync();

  // ---------------- P3: gemm2 — hw2 = h @ W2 (64x64 tile, K=256) ----------------
  for (int vb = bid; vb < 157; vb += GRID) {
    short8* As = (short8*)smem_raw;            // 64 x 4 = 256 short8 (4 KB)
    short8* Bs = (short8*)(smem_raw + 4096);

    const int bm = vb * 64;
    const int l  = t & 63;
    const int wv = t >> 6;
    const int wr = wv >> 1, wc2 = wv & 1;
    const int srow = t >> 2, sslot = t & 3;

    const floatx4 zero = {0.f, 0.f, 0.f, 0.f};
    floatx4 acc[2][2];
    acc[0][0] = zero; acc[0][1] = zero; acc[1][0] = zero; acc[1][1] = zero;

    const int q = l >> 4;

    for (int k0 = 0; k0 < NHID; k0 += 32) {
      short8 av = *(const short8*)&a.h  [(size_t)(bm + srow) * NHID + k0 + sslot * 8];
      short8 bv = *(const short8*)&a.w2t[(size_t)srow * NHID + k0 + sslot * 8];
      __syncthreads();
      As[srow * 4 + (sslot ^ (srow & 3))] = av;
      Bs[srow * 4 + (sslot ^ (srow & 3))] = bv;
      __syncthreads();

      short8 af[2], bf2[2];
#pragma unroll
      for (int mi = 0; mi < 2; mi++) {
        int ar = wr * 32 + mi * 16 + (l & 15);
        af[mi] = As[ar * 4 + (q ^ (ar & 3))];
      }
#pragma unroll
      for (int ni = 0; ni < 2; ni++) {
        int bc = wc2 * 32 + ni * 16 + (l & 15);
        bf2[ni] = Bs[bc * 4 + (q ^ (bc & 3))];
      }
#pragma unroll
      for (int mi = 0; mi < 2; mi++)
#pragma unroll
        for (int ni = 0; ni < 2; ni++)
          acc[mi][ni] = __builtin_amdgcn_mfma_f32_16x16x32_bf16(af[mi], bf2[ni], acc[mi][ni], 0, 0, 0);
    }

#pragma unroll
    for (int mi = 0; mi < 2; mi++)
#pragma unroll
      for (int ni = 0; ni < 2; ni++) {
        int row = bm + wr * 32 + mi * 16 + (l >> 4) * 4;
        int col = wc2 * 32 + ni * 16 + (l & 15);
#pragma unroll
        for (int r = 0; r < 4; r++)
          a.hw2[(size_t)(row + r) * 64 + col] = acc[mi][ni][r];
      }
  }

  grid.sync();

  // ---------------- P4: spmm2 + b2 + log_softmax ----------------
  for (int vb = bid; vb < 2500; vb += GRID) {
    int wave = t >> 6;
    int lane = t & 63;
    int i    = vb * 4 + wave;
    int hh   = lane >> 5;
    int c    = lane & 31;
    bool act = (c * 2 < NCLASS);
    int e0 = i * SLOT;
    int n  = a.cnt[i << 4];
    float a0 = 0.f, a1 = 0.f;
    for (int base = 0; base < n; base += 64) {
      int c2 = n - base; if (c2 > 64) c2 = 64;
      int2 my = make_int2(0, 0);
      if (lane < c2) my = a.epk[e0 + base + lane];
      int j = 0;
      for (; j + 8 <= c2; j += 8) {
#pragma unroll
        for (int p = 0; p < 4; p++) {
          int   idx = j + 2 * p + hh;
          int   s   = __shfl(my.x, idx);
          float wj  = __int_as_float(__shfl(my.y, idx));
          float2 v = *(const float2*)&a.hw2[(size_t)s * 64 + c * 2];
          a0 = fmaf(wj, v.x, a0);
          a1 = fmaf(wj, v.y, a1);
        }
      }
      for (; j < c2; j++) {
        int   s  = __shfl(my.x, j);
        float wj = __int_as_float(__shfl(my.y, j));
        if (hh == 0) {
          float2 v = *(const float2*)&a.hw2[(size_t)s * 64 + c * 2];
          a0 = fmaf(wj, v.x, a0);
          a1 = fmaf(wj, v.y, a1);
        }
      }
    }
    a0 += __shfl_xor(a0, 32);
    a1 += __shfl_xor(a1, 32);
    if (act) { a0 += a.b2[c * 2]; a1 += a.b2[c * 2 + 1]; }
    float mv = act ? fmaxf(a0, a1) : -INFINITY;
#pragma unroll
    for (int o = 16; o > 0; o >>= 1) mv = fmaxf(mv, __shfl_xor(mv, o));
    float ex = act ? (expf(a0 - mv) + expf(a1 - mv)) : 0.f;
#pragma unroll
    for (int o = 16; o > 0; o >>= 1) ex += __shfl_xor(ex, o);
    float ls = logf(ex);
    if (act && hh == 0) {
      float2 o2; o2.x = a0 - mv - ls; o2.y = a1 - mv - ls;
      *(float2*)&a.out[(size_t)i * NCLASS + c * 2] = o2;
    }
  }
}

// ---------------- launcher ----------------

static inline size_t align256(size_t v) { return (v + 255) & ~(size_t)255; }

extern "C" void kernel_launch(void* const* d_in, const int* in_sizes, int n_in,
                              void* d_out, int out_size, void* d_ws, size_t ws_size,
                              hipStream_t stream) {
  char* ws = (char*)d_ws;
  size_t off = 0;
  unsigned short* w1t  = (unsigned short*)(ws + off); off = align256(off + (size_t)NFEAT * NHID * 2);
  unsigned short* w2t  = (unsigned short*)(ws + off); off = align256(off + (size_t)64 * NHID * 2);
  unsigned short* xw1b = (unsigned short*)(ws + off); off = align256(off + (size_t)MPAD * NHID * 2);
  unsigned short* h    = (unsigned short*)(ws + off); off = align256(off + (size_t)MPAD * NHID * 2);
  float* hw2 = (float*)(ws + off); off = align256(off + (size_t)MPAD * 64 * 4);
  int*   cnt = (int*)  (ws + off); off = align256(off + (size_t)N_NODES * CSTRIDE * 4);
  int2*  epk = (int2*) (ws + off); off = align256(off + (size_t)N_NODES * SLOT * 8);

  Args a;
  a.x    = (const float*)d_in[0];
  a.esrc = (const int*)  d_in[1];
  a.edst = (const int*)  d_in[2];
  a.ew   = (const float*)d_in[3];
  a.W1   = (const float*)d_in[4];
  a.b1   = (const float*)d_in[5];
  a.W2   = (const float*)d_in[6];
  a.b2   = (const float*)d_in[7];
  a.out  = (float*)d_out;
  a.w1t = w1t; a.w2t = w2t; a.xw1b = xw1b; a.h = h; a.hw2 = hw2;
  a.cnt = cnt; a.epk = epk;

  void* params[] = { &a };
  hipLaunchCooperativeKernel((const void*)mega_k, dim3(GRID), dim3(256),
                             params, 0, stream);
}

// Round 14
// 69.199 us; speedup vs baseline: 5.0607x; 5.0607x over previous
//
#include <hip/hip_runtime.h>
#include <hip/hip_bf16.h>
#include <math.h>

#define N_NODES 10000
#define MPAD    10112      // 79 * 128
#define N_EDGES 320000
#define NFEAT   512
#define NHID    256
#define NCLASS  40
#define SLOT    96         // max deg bound: Binom(320K,1e-4) max ~55; P(>96) ~ 0
#define CSTRIDE 16         // one counter per 64B line
#define NBM1    158        // gemm1 m-tiles (64 rows each)
#define NG1     (NBM1 * 2) // 316 gemm1 blocks
#define EB      ((N_EDGES + 255) / 256)   // 1250 scatter blocks

typedef short  short8  __attribute__((ext_vector_type(8)));
typedef float  floatx4 __attribute__((ext_vector_type(4)));

__device__ __forceinline__ unsigned short f2b(float f) {
  __hip_bfloat16 h = __float2bfloat16(f);
  unsigned short u; __builtin_memcpy(&u, &h, 2); return u;
}
__device__ __forceinline__ float b2f(unsigned short u) {
  return __uint_as_float(((unsigned)u) << 16);
}
__device__ __forceinline__ short8 pack8(float4 a, float4 b) {
  short8 r;
  r[0] = (short)f2b(a.x); r[1] = (short)f2b(a.y); r[2] = (short)f2b(a.z); r[3] = (short)f2b(a.w);
  r[4] = (short)f2b(b.x); r[5] = (short)f2b(b.y); r[6] = (short)f2b(b.z); r[7] = (short)f2b(b.w);
  return r;
}

// ---------------- prep: W1->bf16 transposed, W2->bf16 transposed+padded,
//                  cnt (padded) -> 0 ----------------

__global__ __launch_bounds__(256) void prep_k(const float* __restrict__ W1,
                                              const float* __restrict__ W2,
                                              unsigned short* __restrict__ w1t,
                                              unsigned short* __restrict__ w2t,
                                              int* __restrict__ cnt) {
  int tid = blockIdx.x * 256 + threadIdx.x;
  if (tid < N_NODES * CSTRIDE) cnt[tid] = 0;
  const int nw1 = NFEAT * NHID;              // 131,072
  if (tid < nw1) {
    int k = tid / NHID, n = tid % NHID;        // coalesced read of W1
    w1t[n * NFEAT + k] = f2b(W1[tid]);         // transposed bf16 write
  } else if (tid < nw1 + 64 * NHID) {
    int j = tid - nw1;
    int n = j >> 8;                            // out-col 0..63
    int k = j & 255;                           // k 0..255
    w2t[j] = (n < NCLASS) ? f2b(W2[k * NCLASS + n]) : (unsigned short)0;
  }
}

// ---------------- fused: GEMM1 64x128 dbuf (blocks < NG1)  ||  slot-scatter ----------------

__global__ __launch_bounds__(256) void gemm1_scatter_k(
    const float* __restrict__ x, const unsigned short* __restrict__ w1t,
    unsigned short* __restrict__ xw1b,
    const int* __restrict__ src, const int* __restrict__ dst,
    const float* __restrict__ w, int* __restrict__ cnt, int2* __restrict__ epk) {
  if (blockIdx.x >= NG1) {
    int e = (blockIdx.x - NG1) * 256 + threadIdx.x;
    if (e < N_EDGES) {
      int d = dst[e];
      int p = atomicAdd(&cnt[d << 4], 1);
      int2 pk; pk.x = src[e]; pk.y = __float_as_int(w[e]);
      epk[d * SLOT + p] = pk;
    }
    return;
  }

  __shared__ short8 As[2][64 * 4];    // 8 KB
  __shared__ short8 Bs[2][128 * 4];   // 16 KB

  const int t  = threadIdx.x;
  const int l  = t & 63;
  const int wc = t >> 6;                    // wave 0..3 -> col strip of 32
  const int bm = (blockIdx.x % NBM1) * 64;
  const int bn = (blockIdx.x / NBM1) * 128;

  const int rowA = t >> 2, sA = t & 3;          // A: 8 floats -> 1 short8 slot
  const int rowB = t >> 1, sB = (t & 1) * 2;    // B: 2 short8 slots

  const float4 z4 = make_float4(0.f, 0.f, 0.f, 0.f);
  const floatx4 zero = {0.f, 0.f, 0.f, 0.f};
  floatx4 acc[4][2];
#pragma unroll
  for (int mi = 0; mi < 4; mi++) { acc[mi][0] = zero; acc[mi][1] = zero; }

  const int q = l >> 4;
  const bool arok = (bm + rowA) < N_NODES;
  const float* xrow = &x[(size_t)(bm + rowA) * NFEAT + sA * 8];
  const unsigned short* brow = &w1t[(size_t)(bn + rowB) * NFEAT + sB * 8];

  {
    float4 a0 = z4, a1 = z4;
    if (arok) { a0 = *(const float4*)(xrow); a1 = *(const float4*)(xrow + 4); }
    short8 b0 = *(const short8*)(brow);
    short8 b1 = *(const short8*)(brow + 8);
    As[0][rowA * 4 + (sA ^ (rowA & 3))] = pack8(a0, a1);
    Bs[0][rowB * 4 + ((sB    ) ^ (rowB & 3))] = b0;
    Bs[0][rowB * 4 + ((sB + 1) ^ (rowB & 3))] = b1;
  }

  for (int s = 0; s < 16; s++) {
    __syncthreads();
    const int cur = s & 1;
    float4 na0 = z4, na1 = z4;
    short8 nb0, nb1;
    const bool more = (s < 15);
    if (more) {
      const int k1 = (s + 1) * 32;
      if (arok) { na0 = *(const float4*)(xrow + k1); na1 = *(const float4*)(xrow + k1 + 4); }
      nb0 = *(const short8*)(brow + k1);
      nb1 = *(const short8*)(brow + k1 + 8);
    }

    short8 af[4], bf[2];
#pragma unroll
    for (int mi = 0; mi < 4; mi++) {
      int ar = mi * 16 + (l & 15);
      af[mi] = As[cur][ar * 4 + (q ^ (ar & 3))];
    }
#pragma unroll
    for (int ni = 0; ni < 2; ni++) {
      int bc = wc * 32 + ni * 16 + (l & 15);
      bf[ni] = Bs[cur][bc * 4 + (q ^ (bc & 3))];
    }
#pragma unroll
    for (int mi = 0; mi < 4; mi++)
#pragma unroll
      for (int ni = 0; ni < 2; ni++)
        acc[mi][ni] = __builtin_amdgcn_mfma_f32_16x16x32_bf16(af[mi], bf[ni], acc[mi][ni], 0, 0, 0);

    if (more) {
      const int nxt = cur ^ 1;
      As[nxt][rowA * 4 + (sA ^ (rowA & 3))] = pack8(na0, na1);
      Bs[nxt][rowB * 4 + ((sB    ) ^ (rowB & 3))] = nb0;
      Bs[nxt][rowB * 4 + ((sB + 1) ^ (rowB & 3))] = nb1;
    }
  }

#pragma unroll
  for (int mi = 0; mi < 4; mi++)
#pragma unroll
    for (int ni = 0; ni < 2; ni++) {
      int row = bm + mi * 16 + (l >> 4) * 4;
      int col = bn + wc * 32 + ni * 16 + (l & 15);
#pragma unroll
      for (int r = 0; r < 4; r++)
        xw1b[(size_t)(row + r) * NHID + col] = f2b(acc[mi][ni][r]);
    }
}

// ---------------- SpMM1: h = bf16(relu(A * xw1 + b1)) ----------------
// Pair-gather: lane = hh<<5 | f; uint2 gather (4 bf16); shfl_xor(32) combine.
// xcd>>2 = slice (L2-resident), xcd&3 = node quarter. 4 nodes/block.

__global__ __launch_bounds__(256) void spmm1_k(const int* __restrict__ cnt,
                                               const int2* __restrict__ epk,
                                               const unsigned short* __restrict__ xw1b,
                                               const float* __restrict__ b1,
                                               unsigned short* __restrict__ h) {
  int bid     = blockIdx.x;
  int xcd     = bid & 7;
  int slice   = xcd >> 2;
  int quarter = xcd & 3;
  int wave    = threadIdx.x >> 6;
  int lane    = threadIdx.x & 63;
  int node    = (bid >> 3) * 4 + wave + quarter * 2500;
  int hh      = lane >> 5;
  int f       = lane & 31;
  int fbase   = slice * 128 + f * 4;

  int e0 = node * SLOT;
  int n  = cnt[node << 4];
  float a0 = 0.f, a1 = 0.f, a2 = 0.f, a3 = 0.f;
  for (int base = 0; base < n; base += 64) {
    int c2 = n - base; if (c2 > 64) c2 = 64;
    int2 my = make_int2(0, 0);
    if (lane < c2) my = epk[e0 + base + lane];
    int j = 0;
    for (; j + 8 <= c2; j += 8) {
#pragma unroll
      for (int p = 0; p < 4; p++) {
        int   idx = j + 2 * p + hh;
        int   s   = __shfl(my.x, idx);
        float wj  = __int_as_float(__shfl(my.y, idx));
        uint2 v = *(const uint2*)&xw1b[(size_t)s * NHID + fbase];
        a0 = fmaf(wj, b2f((unsigned short)(v.x & 0xffff)), a0);
        a1 = fmaf(wj, b2f((unsigned short)(v.x >> 16)),    a1);
        a2 = fmaf(wj, b2f((unsigned short)(v.y & 0xffff)), a2);
        a3 = fmaf(wj, b2f((unsigned short)(v.y >> 16)),    a3);
      }
    }
    for (; j < c2; j++) {
      int   s  = __shfl(my.x, j);
      float wj = __int_as_float(__shfl(my.y, j));
      if (hh == 0) {
        uint2 v = *(const uint2*)&xw1b[(size_t)s * NHID + fbase];
        a0 = fmaf(wj, b2f((unsigned short)(v.x & 0xffff)), a0);
        a1 = fmaf(wj, b2f((unsigned short)(v.x >> 16)),    a1);
        a2 = fmaf(wj, b2f((unsigned short)(v.y & 0xffff)), a2);
        a3 = fmaf(wj, b2f((unsigned short)(v.y >> 16)),    a3);
      }
    }
  }
  a0 += __shfl_xor(a0, 32);
  a1 += __shfl_xor(a1, 32);
  a2 += __shfl_xor(a2, 32);
  a3 += __shfl_xor(a3, 32);
  if (hh == 0) {
    a0 = fmaxf(a0 + b1[fbase + 0], 0.f);
    a1 = fmaxf(a1 + b1[fbase + 1], 0.f);
    a2 = fmaxf(a2 + b1[fbase + 2], 0.f);
    a3 = fmaxf(a3 + b1[fbase + 3], 0.f);
    uint2 po;
    po.x = ((unsigned)f2b(a1) << 16) | f2b(a0);
    po.y = ((unsigned)f2b(a3) << 16) | f2b(a2);
    *(uint2*)&h[(size_t)node * NHID + fbase] = po;
  }
}

// ---------------- GEMM2: hw2 = h @ W2  via MFMA, 64x64 tile, K=256 ----------------

__global__ __launch_bounds__(256) void gemm2_k(const unsigned short* __restrict__ h,
                                               const unsigned short* __restrict__ w2t,
                                               float* __restrict__ hw2) {
  __shared__ short8 As[64 * 4];
  __shared__ short8 Bs[64 * 4];

  const int t  = threadIdx.x;
  const int bm = blockIdx.x * 64;
  const int l  = t & 63;
  const int wv = t >> 6;
  const int wr = wv >> 1, wc = wv & 1;
  const int srow = t >> 2, sslot = t & 3;

  const floatx4 zero = {0.f, 0.f, 0.f, 0.f};
  floatx4 acc[2][2];
  acc[0][0] = zero; acc[0][1] = zero; acc[1][0] = zero; acc[1][1] = zero;

  const int q = l >> 4;

  for (int k0 = 0; k0 < NHID; k0 += 32) {
    short8 av = *(const short8*)&h  [(size_t)(bm + srow) * NHID + k0 + sslot * 8];
    short8 bv = *(const short8*)&w2t[(size_t)srow * NHID + k0 + sslot * 8];
    __syncthreads();
    As[srow * 4 + (sslot ^ (srow & 3))] = av;
    Bs[srow * 4 + (sslot ^ (srow & 3))] = bv;
    __syncthreads();

    short8 af[2], bf2[2];
#pragma unroll
    for (int mi = 0; mi < 2; mi++) {
      int ar = wr * 32 + mi * 16 + (l & 15);
      af[mi] = As[ar * 4 + (q ^ (ar & 3))];
    }
#pragma unroll
    for (int ni = 0; ni < 2; ni++) {
      int bc = wc * 32 + ni * 16 + (l & 15);
      bf2[ni] = Bs[bc * 4 + (q ^ (bc & 3))];
    }
#pragma unroll
    for (int mi = 0; mi < 2; mi++)
#pragma unroll
      for (int ni = 0; ni < 2; ni++)
        acc[mi][ni] = __builtin_amdgcn_mfma_f32_16x16x32_bf16(af[mi], bf2[ni], acc[mi][ni], 0, 0, 0);
  }

#pragma unroll
  for (int mi = 0; mi < 2; mi++)
#pragma unroll
    for (int ni = 0; ni < 2; ni++) {
      int row = bm + wr * 32 + mi * 16 + (l >> 4) * 4;
      int col = wc * 32 + ni * 16 + (l & 15);
#pragma unroll
      for (int r = 0; r < 4; r++)
        hw2[(size_t)(row + r) * 64 + col] = acc[mi][ni][r];
    }
}

// ---------------- SpMM2 + b2 + log_softmax -> out ----------------

__global__ __launch_bounds__(256) void spmm2_k(const int* __restrict__ cnt,
                                               const int2* __restrict__ epk,
                                               const float* __restrict__ hw2,
                                               const float* __restrict__ b2,
                                               float* __restrict__ out) {
  int wave = threadIdx.x >> 6;
  int lane = threadIdx.x & 63;
  int i    = blockIdx.x * 4 + wave;
  int hh   = lane >> 5;
  int c    = lane & 31;                 // classes c*2, c*2+1
  bool act = (c * 2 < NCLASS);          // c < 20
  int e0 = i * SLOT;
  int n  = cnt[i << 4];
  float a0 = 0.f, a1 = 0.f;
  for (int base = 0; base < n; base += 64) {
    int c2 = n - base; if (c2 > 64) c2 = 64;
    int2 my = make_int2(0, 0);
    if (lane < c2) my = epk[e0 + base + lane];
    int j = 0;
    for (; j + 8 <= c2; j += 8) {
#pragma unroll
      for (int p = 0; p < 4; p++) {
        int   idx = j + 2 * p + hh;
        int   s   = __shfl(my.x, idx);
        float wj  = __int_as_float(__shfl(my.y, idx));
        float2 v = *(const float2*)&hw2[(size_t)s * 64 + c * 2];
        a0 = fmaf(wj, v.x, a0);
        a1 = fmaf(wj, v.y, a1);
      }
    }
    for (; j < c2; j++) {
      int   s  = __shfl(my.x, j);
      float wj = __int_as_float(__shfl(my.y, j));
      if (hh == 0) {
        float2 v = *(const float2*)&hw2[(size_t)s * 64 + c * 2];
        a0 = fmaf(wj, v.x, a0);
        a1 = fmaf(wj, v.y, a1);
      }
    }
  }
  a0 += __shfl_xor(a0, 32);
  a1 += __shfl_xor(a1, 32);
  if (act) { a0 += b2[c * 2]; a1 += b2[c * 2 + 1]; }
  float mv = act ? fmaxf(a0, a1) : -INFINITY;
#pragma unroll
  for (int o = 16; o > 0; o >>= 1) mv = fmaxf(mv, __shfl_xor(mv, o));
  float ex = act ? (expf(a0 - mv) + expf(a1 - mv)) : 0.f;
#pragma unroll
  for (int o = 16; o > 0; o >>= 1) ex += __shfl_xor(ex, o);
  float ls = logf(ex);
  if (act && hh == 0) {
    float2 o2; o2.x = a0 - mv - ls; o2.y = a1 - mv - ls;
    *(float2*)&out[(size_t)i * NCLASS + c * 2] = o2;
  }
}

// ---------------- launcher ----------------

static inline size_t align256(size_t v) { return (v + 255) & ~(size_t)255; }

extern "C" void kernel_launch(void* const* d_in, const int* in_sizes, int n_in,
                              void* d_out, int out_size, void* d_ws, size_t ws_size,
                              hipStream_t stream) {
  const float* x        = (const float*)d_in[0];
  const int*   edge_src = (const int*)  d_in[1];
  const int*   edge_dst = (const int*)  d_in[2];
  const float* edge_w   = (const float*)d_in[3];
  const float* W1       = (const float*)d_in[4];
  const float* b1       = (const float*)d_in[5];
  const float* W2       = (const float*)d_in[6];
  const float* b2       = (const float*)d_in[7];
  float* out = (float*)d_out;

  char* ws = (char*)d_ws;
  size_t off = 0;
  unsigned short* w1t  = (unsigned short*)(ws + off); off = align256(off + (size_t)NFEAT * NHID * 2);
  unsigned short* w2t  = (unsigned short*)(ws + off); off = align256(off + (size_t)64 * NHID * 2);
  unsigned short* xw1b = (unsigned short*)(ws + off); off = align256(off + (size_t)MPAD * NHID * 2);
  unsigned short* h    = (unsigned short*)(ws + off); off = align256(off + (size_t)MPAD * NHID * 2);
  float* hw2 = (float*)(ws + off); off = align256(off + (size_t)MPAD * 64 * 4);
  int*   cnt = (int*)  (ws + off); off = align256(off + (size_t)N_NODES * CSTRIDE * 4);
  int2*  epk = (int2*) (ws + off); off = align256(off + (size_t)N_NODES * SLOT * 8);

  const int PREP_ITEMS = N_NODES * CSTRIDE;   // 160000 >= weight items
  prep_k<<<(PREP_ITEMS + 255) / 256, 256, 0, stream>>>(W1, W2, w1t, w2t, cnt);

  gemm1_scatter_k<<<NG1 + EB, 256, 0, stream>>>(x, w1t, xw1b,
                                                edge_src, edge_dst, edge_w, cnt, epk);

  spmm1_k<<<5000, 256, 0, stream>>>(cnt, epk, xw1b, b1, h);

  gemm2_k<<<157, 256, 0, stream>>>(h, w2t, hw2);

  spmm2_k<<<2500, 256, 0, stream>>>(cnt, epk, hw2, b2, out);
}